// Round 15
// baseline (414.780 us; speedup 1.0000x reference)
//
#include <hip/hip_runtime.h>

#define TT 512
#define MM 16      // batch rows per block; grid 256 = 1 block/CU (min-work shape)

typedef _Float16 f16_t;
typedef f16_t f16x8 __attribute__((ext_vector_type(8)));
typedef float  f32x4 __attribute__((ext_vector_type(4)));
typedef unsigned uintx4 __attribute__((ext_vector_type(4)));

#define MFMA16(A, B, C) __builtin_amdgcn_mfma_f32_16x16x32_f16((A), (B), (C), 0, 0, 0)

__device__ __forceinline__ float fr(float x) { return __builtin_amdgcn_rcpf(x); }

#if __has_builtin(__builtin_amdgcn_exp2f)
__device__ __forceinline__ float ex2(float x) { return __builtin_amdgcn_exp2f(x); }
#define EXS 1.44269504f
#else
__device__ __forceinline__ float ex2(float x) { return __expf(x); }
#define EXS 1.0f
#endif

#if __has_builtin(__builtin_amdgcn_cvt_pkrtz)
__device__ __forceinline__ unsigned pk2(float a, float b) {
    auto p = __builtin_amdgcn_cvt_pkrtz(a, b);   // __fp16 ext_vector(2)
    return __builtin_bit_cast(unsigned, p);
}
#else
__device__ __forceinline__ unsigned pk2(float a, float b) {
    unsigned short ha = __builtin_bit_cast(unsigned short, (f16_t)a);
    unsigned short hb = __builtin_bit_cast(unsigned short, (f16_t)b);
    return (unsigned)ha | ((unsigned)hb << 16);
}
#endif

// barrier: LDS-only wait (everything cross-wave is LDS; x loads are lane-private).
__device__ __forceinline__ void bar() {
    asm volatile("s_waitcnt lgkmcnt(0)" ::: "memory");
    __builtin_amdgcn_s_barrier();
    asm volatile("" ::: "memory");
}

// LSTM cell, 7 trans (5 ex2 + 2 rcp), NaN-safe (identical math to R10/R11/R14):
//   c' = (c*u + oa*(C-1)) * rcp(oa*u);  oa = 1+e^-f^, u = (1+e^-i^)(C+1), C = e^2g^
//   h  = (E-1) * rcp((1+D)(E+1)),  E = 2^min(2*EXS*c', 30)
// Biases pre-folded & scaled: bq = { -EXS*bi, -EXS*bf, 2*EXS*bg, -EXS*bo }.
__device__ __forceinline__ float cellEW(float pi, float pf, float pg, float po,
                                        float4 bq, float& c) {
    float A = ex2(fmaf(pf, -EXS, bq.y));
    float B = ex2(fmaf(pi, -EXS, bq.x));
    float C = ex2(fmaf(pg, 2.f * EXS, bq.z));
    float oa = 1.f + A;
    float u  = (1.f + B) * (C + 1.f);
    float cn = fmaf(c, u, oa * (C - 1.f)) * fr(oa * u);
    c = cn;
    float D = ex2(fmaf(po, -EXS, bq.w));
    float E = ex2(fminf(2.f * EXS * cn, 30.f));
    return (E - 1.f) * fr((1.f + D) * (E + 1.f));
}

__device__ __forceinline__ f16x8 cvt8(const float* p) {
    f16x8 r;
#pragma unroll
    for (int e = 0; e < 8; ++e) r[e] = (f16_t)p[e];
    return r;
}

// SWAPPED-OPERAND MFMA (verified R10/R11/R14):
//   A (arg0) = weight tile:  lane l -> gcol = tile + l%16, k = (l/16)*8+e
//   B (arg1) = h:            lane l -> row  = l%16,        k = (l/16)*8+e
//   D:                       lane l -> row  = l%16, gcol-in-tile = (l/16)*4+q
// h-plane [16 rows][64 hcols] f16, byte(row,hcol) = (row*128 + hcol*2) ^ ((row&7)<<4).
//
// R15 structure: 256 threads = 4 waves, ONE wave per SIMD. Wave wv owns h-tile wv
// (hcols wv*16..+15) for BOTH layers: 16 MFMA (gates2(t)) + 12 MFMA (gates1(t+1))
// + 8-cell EW, 1 barrier/step. Source interleaves the a1-MFMA chains with the EW2
// cells (independent) so EW2's VALU/trans ops issue in the a1 matrix-pipe gaps.

__global__ __launch_bounds__(256, 1) void lstm_v15(
    const float* __restrict__ x,
    const float* __restrict__ w_ih0, const float* __restrict__ w_hh0,
    const float* __restrict__ b_ih0, const float* __restrict__ b_hh0,
    const float* __restrict__ w_ih1, const float* __restrict__ w_hh1,
    const float* __restrict__ b_ih1, const float* __restrict__ b_hh1,
    const float* __restrict__ fc1_w, const float* __restrict__ fc1_b,
    const float* __restrict__ fc2_w, const float* __restrict__ fc2_b,
    float* __restrict__ out)
{
    __shared__ __align__(16) unsigned h1p[2][512];   // h1 planes (double buffer)
    __shared__ __align__(16) unsigned h2p[2][512];   // h2 planes
    __shared__ __align__(16) float sH[MM * 68];
    __shared__ float sY[MM * 34];

    const int tid = threadIdx.x;
    const int l   = tid & 63;
    const int wv  = tid >> 6;          // 0..3 = h-tile (one wave per SIMD)
    const int rbase = blockIdx.x * MM;

    const int lc = l & 15;
    const int lq = l >> 4;
    const int hc0  = wv * 16 + lq * 4;
    const int swz  = (lc & 7) << 4;

    const int rdo0 = (lc * 128 + 0 * 64 + lq * 16) ^ swz;
    const int rdo1 = (lc * 128 + 1 * 64 + lq * 16) ^ swz;
    const int wro  = (lc * 128 + hc0 * 2) ^ swz;
    const unsigned xmask = (lq == 0) ? 0xFFFFFFFFu : 0u;

    // ---------------- prologue: BOTH layers' weight A-fragments -> registers ----------------
    f16x8 w1A[4][2];   // w_hh0
    f16x8 wx[4];       // w_ih0 (k=0..3)
    f16x8 w2A[4][2];   // w_ih1
    f16x8 w2B[4][2];   // w_hh1
    float4 bq1[4], bq2[4];
#pragma unroll
    for (int g = 0; g < 4; ++g) {
        const int grow = (g * 64 + wv * 16 + lc) * 64 + lq * 8;
        w1A[g][0] = cvt8(w_hh0 + grow);
        w1A[g][1] = cvt8(w_hh0 + grow + 32);
        w2A[g][0] = cvt8(w_ih1 + grow);
        w2A[g][1] = cvt8(w_ih1 + grow + 32);
        w2B[g][0] = cvt8(w_hh1 + grow);
        w2B[g][1] = cvt8(w_hh1 + grow + 32);
        const int ga = (g * 64 + wv * 16 + lc) * 4;
#pragma unroll
        for (int e = 0; e < 8; ++e)
            wx[g][e] = (e < 4 && lq == 0) ? (f16_t)w_ih0[ga + e] : (f16_t)0.f;
    }
#pragma unroll
    for (int q = 0; q < 4; ++q) {
        const int hc = hc0 + q;
        float b1[4], b2[4];
#pragma unroll
        for (int g = 0; g < 4; ++g) {
            const int ga = g * 64 + hc;
            b1[g] = b_ih0[ga] + b_hh0[ga];
            b2[g] = b_ih1[ga] + b_hh1[ga];
        }
        bq1[q] = make_float4(-EXS * b1[0], -EXS * b1[1], 2.f * EXS * b1[2], -EXS * b1[3]);
        bq2[q] = make_float4(-EXS * b2[0], -EXS * b2[1], 2.f * EXS * b2[2], -EXS * b2[3]);
    }

    float c1[4] = {0.f, 0.f, 0.f, 0.f};
    float c2[4] = {0.f, 0.f, 0.f, 0.f};
    const f32x4 z4 = {0.f, 0.f, 0.f, 0.f};

    const float4* xg = (const float4*)x;
    const size_t xrow = (size_t)(rbase + lc) * TT;
    const float4* xp = xg + xrow + 2;   // next prefetch target = x(2)
    float4 xq = xg[xrow + 1];           // x(t+1) at loop entry (t=0)

    // ---------------- prime: h1(0) from x(0); zero h2 plane 0 ----------------
    {
        float4 x0 = xg[xrow + 0];
        unsigned u0 = pk2(x0.x, x0.y) & xmask, u1 = pk2(x0.z, x0.w) & xmask;
        uintx4 uv = {u0, u1, 0u, 0u};
        f16x8 xf = __builtin_bit_cast(f16x8, uv);
        f32x4 a[4];
#pragma unroll
        for (int g = 0; g < 4; ++g) a[g] = MFMA16(wx[g], xf, z4);
        float hv[4];
#pragma unroll
        for (int q = 0; q < 4; ++q)
            hv[q] = cellEW(a[0][q], a[1][q], a[2][q], a[3][q], bq1[q], c1[q]);
        uint2 w2 = make_uint2(pk2(hv[0], hv[1]), pk2(hv[2], hv[3]));
        *(uint2*)((char*)h1p[0] + wro) = w2;
        h2p[0][tid] = 0;
        h2p[0][256 + tid] = 0;
    }
    __syncthreads();

    // ---------------- step body (flags fold at compile time) ----------------
    auto STEP = [&](const unsigned* h1r, unsigned* h1w,
                    const unsigned* h2r, unsigned* h2w,
                    bool l1act, bool pref, bool lastStore) {
        const char* pl1 = (const char*)h1r;
        const char* pl2 = (const char*)h2r;
        f16x8 hf0 = *(const f16x8*)(pl1 + rdo0);
        f16x8 hf1 = *(const f16x8*)(pl1 + rdo1);
        f16x8 gf0 = *(const f16x8*)(pl2 + rdo0);
        f16x8 gf1 = *(const f16x8*)(pl2 + rdo1);

        // -------- gates2(t): 16 MFMAs, 4 independent chains --------
        f32x4 a2[4];
#pragma unroll
        for (int g = 0; g < 4; ++g) {
            a2[g] = MFMA16(w2A[g][0], hf0, z4);
            a2[g] = MFMA16(w2A[g][1], hf1, a2[g]);
            a2[g] = MFMA16(w2B[g][0], gf0, a2[g]);
            a2[g] = MFMA16(w2B[g][1], gf1, a2[g]);
        }

        // -------- interleave: a1 chains (matrix pipe) with EW2 cells (VALU) --------
        float hv2[4];
        if (l1act) {
            float4 xn;
            if (pref) { xn = *xp; ++xp; }
            unsigned u0 = pk2(xq.x, xq.y) & xmask, u1 = pk2(xq.z, xq.w) & xmask;
            uintx4 uv = {u0, u1, 0u, 0u};
            f16x8 xf = __builtin_bit_cast(f16x8, uv);

            f32x4 a1[4];
#pragma unroll
            for (int j = 0; j < 4; ++j) {
                a1[j] = MFMA16(wx[j], xf, z4);
                a1[j] = MFMA16(w1A[j][0], hf0, a1[j]);
                a1[j] = MFMA16(w1A[j][1], hf1, a1[j]);
                // EW2 cell j is independent of a1 -> issues in the MFMA gaps
                hv2[j] = cellEW(a2[0][j], a2[1][j], a2[2][j], a2[3][j], bq2[j], c2[j]);
            }
            uint2 wh2 = make_uint2(pk2(hv2[0], hv2[1]), pk2(hv2[2], hv2[3]));
            *(uint2*)((char*)h2w + wro) = wh2;

            float hv1[4];
#pragma unroll
            for (int q = 0; q < 4; ++q)
                hv1[q] = cellEW(a1[0][q], a1[1][q], a1[2][q], a1[3][q], bq1[q], c1[q]);
            uint2 wh1 = make_uint2(pk2(hv1[0], hv1[1]), pk2(hv1[2], hv1[3]));
            *(uint2*)((char*)h1w + wro) = wh1;
            if (pref) xq = xn;
        } else {
#pragma unroll
            for (int j = 0; j < 4; ++j)
                hv2[j] = cellEW(a2[0][j], a2[1][j], a2[2][j], a2[3][j], bq2[j], c2[j]);
            uint2 wh2 = make_uint2(pk2(hv2[0], hv2[1]), pk2(hv2[2], hv2[3]));
            *(uint2*)((char*)h2w + wro) = wh2;
        }
        if (lastStore)
            *(float4*)&sH[lc * 68 + hc0] = make_float4(hv2[0], hv2[1], hv2[2], hv2[3]);
        bar();
    };

    // ---------------- main loop: t = 0..509 unrolled x2, then peeled tail ----------------
    for (int it = 0; it < 255; ++it) {
        STEP(h1p[0], h1p[1], h2p[0], h2p[1], true, true, false);   // even t
        STEP(h1p[1], h1p[0], h2p[1], h2p[0], true, true, false);   // odd t
    }
    // t = 510: L1 computes gates1(511) (xq = x(511), no prefetch); h2(510)
    STEP(h1p[0], h1p[1], h2p[0], h2p[1], true, false, false);
    // t = 511: layer-2 only -> h2(511) + sH
    STEP(h1p[1], h1p[0], h2p[1], h2p[0], false, false, true);

    // ---------------- FC head (256 threads) ----------------
    for (int idx = tid; idx < MM * 32; idx += 256) {
        const int r = idx >> 5, mo = idx & 31;
        float s = fc1_b[mo];
#pragma unroll 8
        for (int k = 0; k < 64; ++k) s = fmaf(sH[r * 68 + k], fc1_w[mo * 64 + k], s);
        sY[r * 34 + mo] = fmaxf(s, 0.f);
    }
    __syncthreads();
    if (tid < 32) {
        const int r = tid >> 1, o = tid & 1;
        float s = fc2_b[o];
#pragma unroll 8
        for (int mo = 0; mo < 32; ++mo) s = fmaf(sY[r * 34 + mo], fc2_w[o * 32 + mo], s);
        out[(size_t)(rbase + r) * 2 + o] = fmaxf(s, 0.f);
    }
}

extern "C" void kernel_launch(void* const* d_in, const int* in_sizes, int n_in,
                              void* d_out, int out_size, void* d_ws, size_t ws_size,
                              hipStream_t stream) {
    const float* x     = (const float*)d_in[0];
    const float* w_ih0 = (const float*)d_in[1];
    const float* w_hh0 = (const float*)d_in[2];
    const float* b_ih0 = (const float*)d_in[3];
    const float* b_hh0 = (const float*)d_in[4];
    const float* w_ih1 = (const float*)d_in[5];
    const float* w_hh1 = (const float*)d_in[6];
    const float* b_ih1 = (const float*)d_in[7];
    const float* b_hh1 = (const float*)d_in[8];
    const float* fc1_w = (const float*)d_in[9];
    const float* fc1_b = (const float*)d_in[10];
    const float* fc2_w = (const float*)d_in[11];
    const float* fc2_b = (const float*)d_in[12];
    float* out = (float*)d_out;

    const int nB   = in_sizes[0] / (TT * 4);   // 4096 rows
    const int grid = nB / MM;                  // 256 blocks -> 1/CU

    lstm_v15<<<grid, 256, 0, stream>>>(x, w_ih0, w_hh0, b_ih0, b_hh0,
                                       w_ih1, w_hh1, b_ih1, b_hh1,
                                       fc1_w, fc1_b, fc2_w, fc2_b, out);
}